// Round 1
// baseline (290.224 us; speedup 1.0000x reference)
//
#include <hip/hip_runtime.h>
#include <hip/hip_bf16.h>
#include <math.h>

#define W_  160
#define H_  128
#define HW  20480
#define D_  48
#define C_  32
#define NV  4    // source views (views 1..4)
#define CH  16   // depths per thread in k_warp_sim
#define NCH 3    // 48/16

// ---------------- tiny transform kernel ----------------

__device__ __forceinline__ void fuse_proj(const float* pm, float* P) {
  // pm -> [E(4x4), K(4x4)] for one view. P = E with top 3x4 replaced by K[:3,:3] @ E[:3,:4]
  const float* E = pm;
  const float* K = pm + 16;
  for (int r = 0; r < 3; ++r)
    for (int c = 0; c < 4; ++c)
      P[r*4+c] = K[r*4+0]*E[0*4+c] + K[r*4+1]*E[1*4+c] + K[r*4+2]*E[2*4+c];
  for (int c = 0; c < 4; ++c) P[12+c] = E[12+c];
}

__device__ void invert4(const float* m, float* invOut) {
  float inv[16];
  inv[0]  =  m[5]*m[10]*m[15] - m[5]*m[11]*m[14] - m[9]*m[6]*m[15] + m[9]*m[7]*m[14] + m[13]*m[6]*m[11] - m[13]*m[7]*m[10];
  inv[4]  = -m[4]*m[10]*m[15] + m[4]*m[11]*m[14] + m[8]*m[6]*m[15] - m[8]*m[7]*m[14] - m[12]*m[6]*m[11] + m[12]*m[7]*m[10];
  inv[8]  =  m[4]*m[9]*m[15]  - m[4]*m[11]*m[13] - m[8]*m[5]*m[15] + m[8]*m[7]*m[13] + m[12]*m[5]*m[11] - m[12]*m[7]*m[9];
  inv[12] = -m[4]*m[9]*m[14]  + m[4]*m[10]*m[13] + m[8]*m[5]*m[14] - m[8]*m[6]*m[13] - m[12]*m[5]*m[10] + m[12]*m[6]*m[9];
  inv[1]  = -m[1]*m[10]*m[15] + m[1]*m[11]*m[14] + m[9]*m[2]*m[15] - m[9]*m[3]*m[14] - m[13]*m[2]*m[11] + m[13]*m[3]*m[10];
  inv[5]  =  m[0]*m[10]*m[15] - m[0]*m[11]*m[14] - m[8]*m[2]*m[15] + m[8]*m[3]*m[14] + m[12]*m[2]*m[11] - m[12]*m[3]*m[10];
  inv[9]  = -m[0]*m[9]*m[15]  + m[0]*m[11]*m[13] + m[8]*m[1]*m[15] - m[8]*m[3]*m[13] - m[12]*m[1]*m[11] + m[12]*m[3]*m[9];
  inv[13] =  m[0]*m[9]*m[14]  - m[0]*m[10]*m[13] - m[8]*m[1]*m[14] + m[8]*m[2]*m[13] + m[12]*m[1]*m[10] - m[12]*m[2]*m[9];
  inv[2]  =  m[1]*m[6]*m[15]  - m[1]*m[7]*m[14]  - m[5]*m[2]*m[15] + m[5]*m[3]*m[14] + m[13]*m[2]*m[7]  - m[13]*m[3]*m[6];
  inv[6]  = -m[0]*m[6]*m[15]  + m[0]*m[7]*m[14]  + m[4]*m[2]*m[15] - m[4]*m[3]*m[14] - m[12]*m[2]*m[7]  + m[12]*m[3]*m[6];
  inv[10] =  m[0]*m[5]*m[15]  - m[0]*m[7]*m[13]  - m[4]*m[1]*m[15] + m[4]*m[3]*m[13] + m[12]*m[1]*m[7]  - m[12]*m[3]*m[5];
  inv[14] = -m[0]*m[5]*m[14]  + m[0]*m[6]*m[13]  + m[4]*m[1]*m[14] - m[4]*m[2]*m[13] - m[12]*m[1]*m[6]  + m[12]*m[2]*m[5];
  inv[3]  = -m[1]*m[6]*m[11]  + m[1]*m[7]*m[10]  + m[5]*m[2]*m[11] - m[5]*m[3]*m[10] - m[9]*m[2]*m[7]   + m[9]*m[3]*m[6];
  inv[7]  =  m[0]*m[6]*m[11]  - m[0]*m[7]*m[10]  - m[4]*m[2]*m[11] + m[4]*m[3]*m[10] + m[8]*m[2]*m[7]   - m[8]*m[3]*m[6];
  inv[11] = -m[0]*m[5]*m[11]  + m[0]*m[7]*m[9]   + m[4]*m[1]*m[11] - m[4]*m[3]*m[9]  - m[8]*m[1]*m[7]   + m[8]*m[3]*m[5];
  inv[15] =  m[0]*m[5]*m[10]  - m[0]*m[6]*m[9]   - m[4]*m[1]*m[10] + m[4]*m[2]*m[9]  + m[8]*m[1]*m[6]   - m[8]*m[2]*m[5];
  float det = m[0]*inv[0] + m[1]*inv[4] + m[2]*inv[8] + m[3]*inv[12];
  det = 1.0f / det;
  for (int i = 0; i < 16; i++) invOut[i] = inv[i] * det;
}

// xf layout per src view v (0..3): [r00 r01 r02 r10 r11 r12 r20 r21 r22 t0 t1 t2]
__global__ void k_xform(const float* __restrict__ pm, float* __restrict__ xf) {
  if (blockIdx.x || threadIdx.x) return;
  float Pr[16], Pinv[16], Ps[16], M[16];
  fuse_proj(pm, Pr);
  invert4(Pr, Pinv);
  for (int v = 1; v <= NV; ++v) {
    fuse_proj(pm + v*32, Ps);
    for (int r = 0; r < 4; ++r)
      for (int c = 0; c < 4; ++c) {
        float a = 0.f;
        for (int k = 0; k < 4; ++k) a += Ps[r*4+k]*Pinv[k*4+c];
        M[r*4+c] = a;
      }
    float* o = xf + (v-1)*12;
    o[0]=M[0];  o[1]=M[1];  o[2]=M[2];
    o[3]=M[4];  o[4]=M[5];  o[5]=M[6];
    o[6]=M[8];  o[7]=M[9];  o[8]=M[10];
    o[9]=M[3];  o[10]=M[7]; o[11]=M[11];
  }
}

// ---------------- transpose (V,C,H,W) -> (V,HW,C) ----------------
__global__ void k_transpose(const float* __restrict__ feat, float* __restrict__ tf) {
  int idx = blockIdx.x*blockDim.x + threadIdx.x;
  if (idx >= 5*HW) return;
  int p = idx % HW;
  int v = idx / HW;
  const float* src = feat + (size_t)v*C_*HW + p;
  float4* dst = (float4*)(tf + ((size_t)v*HW + p)*C_);
  #pragma unroll
  for (int c0 = 0; c0 < C_; c0 += 4) {
    float4 t;
    t.x = src[(size_t)(c0+0)*HW];
    t.y = src[(size_t)(c0+1)*HW];
    t.z = src[(size_t)(c0+2)*HW];
    t.w = src[(size_t)(c0+3)*HW];
    dst[c0/4] = t;
  }
}

// ---------------- main warp + similarity + MLP kernel ----------------
__global__ void __launch_bounds__(256)
k_warp_sim(const float* __restrict__ tf, const float* __restrict__ dv,
           const float* __restrict__ xf,
           const float* __restrict__ w0, const float* __restrict__ b0,
           const float* __restrict__ w1, const float* __restrict__ b1,
           const float* __restrict__ w2, const float* __restrict__ b2,
           float* __restrict__ sim_all, float* __restrict__ yp) {
  int idx = blockIdx.x*blockDim.x + threadIdx.x;   // (chunk, v, p), p fastest
  if (idx >= NV*NCH*HW) return;
  int p = idx % HW;
  int t = idx / HW;
  int v = t & 3;
  int chunk = t >> 2;

  float xpix = (float)(p % W_);
  float ypix = (float)(p / W_);

  const float* M = xf + v*12;
  float rx = M[0]*xpix + M[1]*ypix + M[2];
  float ry = M[3]*xpix + M[4]*ypix + M[5];
  float rz = M[6]*xpix + M[7]*ypix + M[8];
  float t0 = M[9], t1 = M[10], t2 = M[11];

  // ref feature vector (view 0)
  float rf[C_];
  {
    const float4* rq = (const float4*)(tf + (size_t)p*C_);
    #pragma unroll
    for (int c4 = 0; c4 < C_/4; ++c4) {
      float4 q = rq[c4];
      rf[c4*4+0]=q.x; rf[c4*4+1]=q.y; rf[c4*4+2]=q.z; rf[c4*4+3]=q.w;
    }
  }
  const float* srcb = tf + (size_t)(v+1)*HW*C_;

  float ymax = -3.0e38f;
  #pragma unroll 1
  for (int dd = 0; dd < CH; ++dd) {
    int d = chunk*CH + dd;
    float depth = dv[(size_t)d*HW + p];
    float X = rx*depth + t0;
    float Y = ry*depth + t1;
    float Z = rz*depth + t2;
    float px = X / Z;
    float py = Y / Z;

    float x0f = floorf(px), y0f = floorf(py);
    float x1f = x0f + 1.0f, y1f = y0f + 1.0f;
    float wx1 = px - x0f, wx0 = 1.0f - wx1;
    float wy1 = py - y0f, wy0 = 1.0f - wy1;
    bool vx0 = (x0f >= 0.0f) && (x0f <= (float)(W_-1));
    bool vx1 = (x1f >= 0.0f) && (x1f <= (float)(W_-1));
    bool vy0 = (y0f >= 0.0f) && (y0f <= (float)(H_-1));
    bool vy1 = (y1f >= 0.0f) && (y1f <= (float)(H_-1));
    int cx0 = (int)fminf(fmaxf(x0f, 0.0f), (float)(W_-1));
    int cx1 = (int)fminf(fmaxf(x1f, 0.0f), (float)(W_-1));
    int cy0 = (int)fminf(fmaxf(y0f, 0.0f), (float)(H_-1));
    int cy1 = (int)fminf(fmaxf(y1f, 0.0f), (float)(H_-1));
    float w00 = wx0*wy0*((vx0&&vy0)?1.f:0.f);
    float w01 = wx1*wy0*((vx1&&vy0)?1.f:0.f);
    float w10 = wx0*wy1*((vx0&&vy1)?1.f:0.f);
    float w11 = wx1*wy1*((vx1&&vy1)?1.f:0.f);

    const float4* q00 = (const float4*)(srcb + (size_t)(cy0*W_+cx0)*C_);
    const float4* q01 = (const float4*)(srcb + (size_t)(cy0*W_+cx1)*C_);
    const float4* q10 = (const float4*)(srcb + (size_t)(cy1*W_+cx0)*C_);
    const float4* q11 = (const float4*)(srcb + (size_t)(cy1*W_+cx1)*C_);

    float d00=0.f, d01=0.f, d10=0.f, d11=0.f;
    #pragma unroll
    for (int c4 = 0; c4 < C_/4; ++c4) {
      float4 a = q00[c4], b = q01[c4], g = q10[c4], e = q11[c4];
      d00 += a.x*rf[c4*4+0] + a.y*rf[c4*4+1] + a.z*rf[c4*4+2] + a.w*rf[c4*4+3];
      d01 += b.x*rf[c4*4+0] + b.y*rf[c4*4+1] + b.z*rf[c4*4+2] + b.w*rf[c4*4+3];
      d10 += g.x*rf[c4*4+0] + g.y*rf[c4*4+1] + g.z*rf[c4*4+2] + g.w*rf[c4*4+3];
      d11 += e.x*rf[c4*4+0] + e.y*rf[c4*4+1] + e.z*rf[c4*4+2] + e.w*rf[c4*4+3];
    }
    float sim = (w00*d00 + w01*d01 + w10*d10 + w11*d11) * (1.0f/(float)C_);

    sim_all[(size_t)(v*D_ + d)*HW + p] = sim;

    // MLP: 1 -> 16 -> 8 -> 1
    float h0[16];
    #pragma unroll
    for (int o = 0; o < 16; ++o) h0[o] = fmaxf(w0[o]*sim + b0[o], 0.0f);
    float yv = b2[0];
    #pragma unroll
    for (int j = 0; j < 8; ++j) {
      float a = b1[j];
      #pragma unroll
      for (int o = 0; o < 16; ++o) a += w1[j*16+o]*h0[o];
      yv += w2[j]*fmaxf(a, 0.0f);
    }
    ymax = fmaxf(ymax, yv);
  }
  yp[(size_t)(v*NCH + chunk)*HW + p] = ymax;
}

// ---------------- view weight: sigmoid(max over chunks) ----------------
__global__ void k_vw(const float* __restrict__ yp, float* __restrict__ vw,
                     float* __restrict__ out) {
  int idx = blockIdx.x*blockDim.x + threadIdx.x;   // (v,p)
  if (idx >= NV*HW) return;
  int p = idx % HW;
  int v = idx / HW;
  float m = yp[(size_t)(v*NCH+0)*HW + p];
  m = fmaxf(m, yp[(size_t)(v*NCH+1)*HW + p]);
  m = fmaxf(m, yp[(size_t)(v*NCH+2)*HW + p]);
  float s = 1.0f / (1.0f + expf(-m));
  vw[(size_t)v*HW + p] = s;
  // view_weights output region: after depth(HW)+conf(HW)+prob(D*HW)
  out[(size_t)(2*HW + D_*HW) + (size_t)v*HW + p] = s;
}

// ---------------- fuse views ----------------
__global__ void k_fuse(const float* __restrict__ sim_all, const float* __restrict__ vw,
                       float* __restrict__ fus) {
  int idx = blockIdx.x*blockDim.x + threadIdx.x;   // (d,p)
  if (idx >= D_*HW) return;
  int p = idx % HW;
  int d = idx / HW;
  float wsum = 1e-5f;
  float ssum = 0.0f;
  #pragma unroll
  for (int v = 0; v < NV; ++v) {
    float s = sim_all[(size_t)(v*D_ + d)*HW + p];
    float w = vw[(size_t)v*HW + p];
    ssum += s*w;
    wsum += w;
  }
  fus[(size_t)d*HW + p] = ssum / wsum;
}

// ---------------- 3x3x3 conv (cross-correlation, zero pad SAME) ----------------
__global__ void k_conv(const float* __restrict__ fus, const float* __restrict__ rw,
                       const float* __restrict__ rb, float* __restrict__ cost) {
  int idx = blockIdx.x*blockDim.x + threadIdx.x;   // (d,p)
  if (idx >= D_*HW) return;
  int p = idx % HW;
  int d = idx / HW;
  int x = p % W_;
  int y = p / W_;
  float acc = rb[0];
  #pragma unroll
  for (int kd = 0; kd < 3; ++kd) {
    int dz = d + kd - 1;
    if (dz < 0 || dz >= D_) continue;
    #pragma unroll
    for (int kh = 0; kh < 3; ++kh) {
      int yy = y + kh - 1;
      if (yy < 0 || yy >= H_) continue;
      #pragma unroll
      for (int kw = 0; kw < 3; ++kw) {
        int xx = x + kw - 1;
        if (xx < 0 || xx >= W_) continue;
        acc += fus[(size_t)dz*HW + yy*W_ + xx] * rw[(kd*3+kh)*3+kw];
      }
    }
  }
  cost[(size_t)d*HW + p] = acc;
}

// ---------------- softmax / argmax / outputs ----------------
__global__ void k_softmax(const float* __restrict__ cost, const float* __restrict__ dv,
                          float* __restrict__ out) {
  int p = blockIdx.x*blockDim.x + threadIdx.x;
  if (p >= HW) return;
  float vbuf[D_];
  #pragma unroll
  for (int d = 0; d < D_; ++d) vbuf[d] = cost[(size_t)d*HW + p];
  float vmax = vbuf[0];
  int am = 0;
  #pragma unroll
  for (int d = 1; d < D_; ++d) {
    if (vbuf[d] > vmax) { vmax = vbuf[d]; am = d; }
  }
  float sum = 0.0f;
  #pragma unroll
  for (int d = 0; d < D_; ++d) {
    float e = expf(vbuf[d] - vmax);
    vbuf[d] = e;
    sum += e;
  }
  float inv = 1.0f / sum;
  #pragma unroll
  for (int d = 0; d < D_; ++d) {
    out[(size_t)(2*HW) + (size_t)d*HW + p] = vbuf[d] * inv;   // prob
  }
  out[p] = dv[(size_t)am*HW + p];   // depth at argmax
  out[HW + p] = inv;                // conf = max prob = exp(0)/sum
}

// ---------------- launch ----------------
extern "C" void kernel_launch(void* const* d_in, const int* in_sizes, int n_in,
                              void* d_out, int out_size, void* d_ws, size_t ws_size,
                              hipStream_t stream) {
  const float* feat = (const float*)d_in[0];
  const float* pm   = (const float*)d_in[1];
  const float* dv   = (const float*)d_in[2];
  const float* w0   = (const float*)d_in[3];
  const float* b0   = (const float*)d_in[4];
  const float* w1   = (const float*)d_in[5];
  const float* b1   = (const float*)d_in[6];
  const float* w2   = (const float*)d_in[7];
  const float* b2   = (const float*)d_in[8];
  const float* rw   = (const float*)d_in[9];
  const float* rb   = (const float*)d_in[10];
  float* out = (float*)d_out;
  float* ws  = (float*)d_ws;

  // workspace layout (floats)
  float* xf   = ws;                  // 48  (pad 64)
  float* tf   = ws + 64;             // 5*HW*C = 3,276,800
  float* sim  = ws + 3276864;        // 4*48*HW = 3,932,160
  float* yp   = ws + 7209024;        // 4*3*HW = 245,760
  float* vw   = ws + 7454784;        // 4*HW = 81,920
  float* fus  = ws + 7536704;        // 48*HW = 983,040
  float* cost = ws + 8519744;        // 48*HW = 983,040
  // total 9,502,784 floats = ~36.3 MB

  hipLaunchKernelGGL(k_xform, dim3(1), dim3(64), 0, stream, pm, xf);
  hipLaunchKernelGGL(k_transpose, dim3((5*HW)/256), dim3(256), 0, stream, feat, tf);
  hipLaunchKernelGGL(k_warp_sim, dim3((NV*NCH*HW)/256), dim3(256), 0, stream,
                     tf, dv, xf, w0, b0, w1, b1, w2, b2, sim, yp);
  hipLaunchKernelGGL(k_vw, dim3((NV*HW)/256), dim3(256), 0, stream, yp, vw, out);
  hipLaunchKernelGGL(k_fuse, dim3((D_*HW)/256), dim3(256), 0, stream, sim, vw, fus);
  hipLaunchKernelGGL(k_conv, dim3((D_*HW)/256), dim3(256), 0, stream, fus, rw, rb, cost);
  hipLaunchKernelGGL(k_softmax, dim3(HW/256), dim3(256), 0, stream, cost, dv, out);
}